// Round 1
// baseline (2189.402 us; speedup 1.0000x reference)
//
#include <hip/hip_runtime.h>
#include <math.h>

#define N_NODES 50000
#define N_EDGES 800000
#define H 96
#define QKV_N 288

#define NPB1 32   // nodes per block, qkv kernel
#define EPB  32   // edges per block, edge kernel  (800000 % 32 == 0)
#define NPB3 32   // nodes per block, node kernel

// ---------------------------------------------------------------------------
// Kernel 1: qkv[n, t] = dot(x[n, :], qkv_w[t, :]) + qkv_b[t]   (t < 288)
// One thread per output column; weight row lives in 96 VGPRs, reused across
// NPB1 nodes. x row staged in LDS, consumed as broadcast float4 reads.
// ---------------------------------------------------------------------------
__global__ __launch_bounds__(QKV_N) void qkv_kernel(
    const float* __restrict__ x, const float* __restrict__ qw,
    const float* __restrict__ qb, float* __restrict__ qkv)
{
    __shared__ __align__(16) float xs[H];
    const int t = threadIdx.x;

    float w[H];
    #pragma unroll
    for (int k4 = 0; k4 < H; k4 += 4) {
        float4 v = *(const float4*)(qw + (size_t)t * H + k4);
        w[k4] = v.x; w[k4 + 1] = v.y; w[k4 + 2] = v.z; w[k4 + 3] = v.w;
    }
    const float bias = qb[t];

    const int n0 = blockIdx.x * NPB1;
    for (int nn = 0; nn < NPB1; ++nn) {
        const int node = n0 + nn;
        if (node >= N_NODES) break;          // block-uniform
        __syncthreads();
        if (t < H) xs[t] = x[(size_t)node * H + t];
        __syncthreads();
        float acc = bias;
        #pragma unroll
        for (int k4 = 0; k4 < H; k4 += 4) {
            float4 c = *(const float4*)(xs + k4);
            acc += c.x * w[k4] + c.y * w[k4 + 1] + c.z * w[k4 + 2] + c.w * w[k4 + 3];
        }
        qkv[(size_t)node * QKV_N + t] = acc;
    }
}

// ---------------------------------------------------------------------------
// Kernel 2: per edge e:
//   Eh[t]      = dot(conn[e,:], e_w[t,:]) + e_b[t]     (t < 192, Ew=0..95 Eb=96..191)
//   c1         = (Q[dst] + K[src]) * Ew
//   conn_out   = relu(sign(c1)*sqrt(|c1|) + Eb)
//   atomic:      agg[dst]  += V[src];  eagg[dst] += conn_out
//   out_e[e]   = layernorm(conn[e] + conn_out)         (fused: conn_out never hits HBM)
// ---------------------------------------------------------------------------
__global__ __launch_bounds__(192) void edge_kernel(
    const float* __restrict__ conn, const int* __restrict__ eidx,
    const float* __restrict__ qkv,
    const float* __restrict__ ew, const float* __restrict__ eb,
    const float* __restrict__ ln_g, const float* __restrict__ ln_b,
    float* __restrict__ agg, float* __restrict__ eagg,
    float* __restrict__ out_e)
{
    __shared__ __align__(16) float cs[H];     // conn row
    __shared__ float eh[2 * H];               // Ew | Eb
    __shared__ float red0[H], red1[H];        // LN reduction
    const int t = threadIdx.x;

    float w[H];
    #pragma unroll
    for (int k4 = 0; k4 < H; k4 += 4) {
        float4 v = *(const float4*)(ew + (size_t)t * H + k4);
        w[k4] = v.x; w[k4 + 1] = v.y; w[k4 + 2] = v.z; w[k4 + 3] = v.w;
    }
    const float bias = eb[t];
    const float lg = (t < H) ? ln_g[t] : 0.f;
    const float lb = (t < H) ? ln_b[t] : 0.f;

    const int e0 = blockIdx.x * EPB;
    for (int ee = 0; ee < EPB; ++ee) {
        const int e = e0 + ee;
        __syncthreads();                       // protect LDS reuse across iters
        if (t < H) cs[t] = conn[(size_t)e * H + t];
        __syncthreads();

        // 192-wide GEMV: Eh row
        {
            float acc = bias;
            #pragma unroll
            for (int k4 = 0; k4 < H; k4 += 4) {
                float4 c = *(const float4*)(cs + k4);
                acc += c.x * w[k4] + c.y * w[k4 + 1] + c.z * w[k4 + 2] + c.w * w[k4 + 3];
            }
            eh[t] = acc;
        }
        __syncthreads();

        float val = 0.f;                       // e = conn + conn_out (held in reg)
        if (t < H) {
            const int dst = eidx[e];
            const int src = eidx[N_EDGES + e];
            const float q  = qkv[(size_t)dst * QKV_N + t];
            const float kk = qkv[(size_t)src * QKV_N + H + t];
            const float vv = qkv[(size_t)src * QKV_N + 2 * H + t];
            const float c1 = (q + kk) * eh[t];
            const float c2 = copysignf(sqrtf(fabsf(c1)), c1);
            float co = c2 + eh[H + t];
            co = co > 0.f ? co : 0.f;          // relu
            unsafeAtomicAdd(&agg[(size_t)dst * H + t], vv);
            unsafeAtomicAdd(&eagg[(size_t)dst * H + t], co);
            val = cs[t] + co;
            red0[t] = val;
            red1[t] = val * val;
        }
        __syncthreads();
        if (t < 32) { red0[t] += red0[t + 64]; red1[t] += red1[t + 64]; }
        __syncthreads();
        for (int s = 32; s > 0; s >>= 1) {
            if (t < s) { red0[t] += red0[t + s]; red1[t] += red1[t + s]; }
            __syncthreads();
        }
        if (t < H) {
            const float mean = red0[0] * (1.f / H);
            const float var  = red1[0] * (1.f / H) - mean * mean;
            const float r    = rsqrtf(var + 1e-5f);
            out_e[(size_t)e * H + t] = (val - mean) * r * lg + lb;
        }
    }
}

// ---------------------------------------------------------------------------
// Kernel 3: per node n:
//   e2   = eagg[n] @ conn_lin_w.T + conn_lin_b
//   h    = (agg[n] + e2) @ nodelin_w.T + nodelin_b + x[n]
//   out_h[n] = layernorm(h)
// threads 0..95 own conn_lin rows, threads 96..191 own nodelin rows (regs).
// ---------------------------------------------------------------------------
__global__ __launch_bounds__(192) void node_kernel(
    const float* __restrict__ x,
    const float* __restrict__ agg, const float* __restrict__ eagg,
    const float* __restrict__ clw, const float* __restrict__ clb,
    const float* __restrict__ nlw, const float* __restrict__ nlb,
    const float* __restrict__ ln_g, const float* __restrict__ ln_b,
    float* __restrict__ out_h)
{
    __shared__ __align__(16) float ga[H];     // eagg row
    __shared__ __align__(16) float sa[H];     // agg row, then agg+e2
    __shared__ float red0[H], red1[H];
    const int t = threadIdx.x;

    float w[H];
    {
        const float* wsrc = (t < H) ? (clw + (size_t)t * H) : (nlw + (size_t)(t - H) * H);
        #pragma unroll
        for (int k4 = 0; k4 < H; k4 += 4) {
            float4 v = *(const float4*)(wsrc + k4);
            w[k4] = v.x; w[k4 + 1] = v.y; w[k4 + 2] = v.z; w[k4 + 3] = v.w;
        }
    }
    const float bias = (t < H) ? clb[t] : nlb[t - H];
    const float lg = (t >= H) ? ln_g[t - H] : 0.f;
    const float lb = (t >= H) ? ln_b[t - H] : 0.f;

    const int n0 = blockIdx.x * NPB3;
    for (int nn = 0; nn < NPB3; ++nn) {
        const int node = n0 + nn;
        if (node >= N_NODES) break;            // block-uniform
        __syncthreads();
        if (t < H)       ga[t]     = eagg[(size_t)node * H + t];
        else             sa[t - H] = agg[(size_t)node * H + (t - H)];
        __syncthreads();

        if (t < H) {                           // e2 GEMV, s = agg + e2
            float acc = bias;
            #pragma unroll
            for (int k4 = 0; k4 < H; k4 += 4) {
                float4 c = *(const float4*)(ga + k4);
                acc += c.x * w[k4] + c.y * w[k4 + 1] + c.z * w[k4 + 2] + c.w * w[k4 + 3];
            }
            sa[t] += acc;
        }
        __syncthreads();

        float val = 0.f;
        if (t >= H) {                          // h GEMV + residual
            const int tt = t - H;
            float acc = bias;
            #pragma unroll
            for (int k4 = 0; k4 < H; k4 += 4) {
                float4 c = *(const float4*)(sa + k4);
                acc += c.x * w[k4] + c.y * w[k4 + 1] + c.z * w[k4 + 2] + c.w * w[k4 + 3];
            }
            val = acc + x[(size_t)node * H + tt];
            red0[tt] = val;
            red1[tt] = val * val;
        }
        __syncthreads();
        if (t < 32) { red0[t] += red0[t + 64]; red1[t] += red1[t + 64]; }
        __syncthreads();
        for (int s = 32; s > 0; s >>= 1) {
            if (t < s) { red0[t] += red0[t + s]; red1[t] += red1[t + s]; }
            __syncthreads();
        }
        if (t >= H) {
            const float mean = red0[0] * (1.f / H);
            const float var  = red1[0] * (1.f / H) - mean * mean;
            const float r    = rsqrtf(var + 1e-5f);
            out_h[(size_t)node * H + (t - H)] = (val - mean) * r * lg + lb;
        }
    }
}

// ---------------------------------------------------------------------------
extern "C" void kernel_launch(void* const* d_in, const int* in_sizes, int n_in,
                              void* d_out, int out_size, void* d_ws, size_t ws_size,
                              hipStream_t stream) {
    const float* x      = (const float*)d_in[0];
    const float* conn   = (const float*)d_in[1];
    const int*   eidx   = (const int*)  d_in[2];
    const float* qkv_w  = (const float*)d_in[3];
    const float* qkv_b  = (const float*)d_in[4];
    const float* e_w    = (const float*)d_in[5];
    const float* e_b    = (const float*)d_in[6];
    const float* clw    = (const float*)d_in[7];
    const float* clb    = (const float*)d_in[8];
    const float* nlw    = (const float*)d_in[9];
    const float* nlb    = (const float*)d_in[10];
    const float* ln_h_g = (const float*)d_in[11];
    const float* ln_h_b = (const float*)d_in[12];
    const float* ln_e_g = (const float*)d_in[13];
    const float* ln_e_b = (const float*)d_in[14];

    float* ws   = (float*)d_ws;
    float* qkv  = ws;                                    // 50000*288 = 14.4M f32
    float* agg  = ws + (size_t)N_NODES * QKV_N;          // 4.8M f32
    float* eagg = agg + (size_t)N_NODES * H;             // 4.8M f32

    float* out_h = (float*)d_out;                        // 50000*96
    float* out_e = out_h + (size_t)N_NODES * H;          // 800000*96

    // zero the two accumulators (ws is poisoned 0xAA by the harness)
    hipMemsetAsync(agg, 0, 2ull * N_NODES * H * sizeof(float), stream);

    qkv_kernel <<<(N_NODES + NPB1 - 1) / NPB1, QKV_N, 0, stream>>>(x, qkv_w, qkv_b, qkv);
    edge_kernel<<<N_EDGES / EPB,               192,   0, stream>>>(conn, eidx, qkv, e_w, e_b,
                                                                   ln_e_g, ln_e_b, agg, eagg, out_e);
    node_kernel<<<(N_NODES + NPB3 - 1) / NPB3, 192,   0, stream>>>(x, agg, eagg, clw, clb,
                                                                   nlw, nlb, ln_h_g, ln_h_b, out_h);
}